// Round 5
// baseline (733.955 us; speedup 1.0000x reference)
//
#include <hip/hip_runtime.h>

#define Bb 2
#define Ss 1024
#define Dd 1024
#define Ll 512
#define Hh 16
#define HDd 32
#define Ff 2048
#define Ee 8
#define Tt 2048   // B*S
#define EPSf 1e-5f
#define THETAf 10000.0f

typedef unsigned short u16;
typedef unsigned int u32;
typedef short s16x8 __attribute__((ext_vector_type(8)));
typedef float f32x4 __attribute__((ext_vector_type(4)));

__device__ __forceinline__ float bf2f(u16 u) {
    union { u32 i; float f; } v; v.i = ((u32)u) << 16; return v.f;
}
__device__ __forceinline__ u16 f2bf(float f) {
    union { float f; u32 i; } v; v.f = f;
    u32 u = v.i;
    u32 r = (u + 0x7FFFu + ((u >> 16) & 1u)) >> 16;
    return (u16)r;
}

// ---------------------------------------------------------------------------
__global__ __launch_bounds__(256) void rmsnorm1_k(const float* __restrict__ x,
                                                  const float* __restrict__ g,
                                                  u16* __restrict__ hhi,
                                                  u16* __restrict__ hlo) {
    int row = blockIdx.x, tid = threadIdx.x;
    __shared__ float red[256];
    float xv[4]; float ss = 0.f;
    #pragma unroll
    for (int i = 0; i < 4; i++) {
        int d = tid + i * 256;
        xv[i] = x[(size_t)row * Dd + d];
        ss += xv[i] * xv[i];
    }
    red[tid] = ss; __syncthreads();
    for (int s2 = 128; s2 > 0; s2 >>= 1) {
        if (tid < s2) red[tid] += red[tid + s2];
        __syncthreads();
    }
    float scale = rsqrtf(red[0] / (float)Dd + EPSf);
    #pragma unroll
    for (int i = 0; i < 4; i++) {
        int d = tid + i * 256;
        float h = xv[i] * g[d] * scale;
        u16 hi = f2bf(h);
        hhi[(size_t)row * Dd + d] = hi;
        hlo[(size_t)row * Dd + d] = f2bf(h - bf2f(hi));
    }
}

// rmsnorm2 + fused router (pure-f32 logits; np top-k fidelity)
__global__ __launch_bounds__(256) void rmsnorm2_router_k(
    const float* __restrict__ x2, const float* __restrict__ g,
    const float* __restrict__ rw, u16* __restrict__ t2h,
    float* __restrict__ gate_w, int* __restrict__ counts,
    int* __restrict__ list_tok, int* __restrict__ list_gid) {
    int row = blockIdx.x, tid = threadIdx.x;
    __shared__ float red[256];
    __shared__ float pw[4][8];
    float xv[4]; float ss = 0.f;
    #pragma unroll
    for (int i = 0; i < 4; i++) {
        int d = tid + i * 256;
        xv[i] = x2[(size_t)row * Dd + d];
        ss += xv[i] * xv[i];
    }
    red[tid] = ss; __syncthreads();
    for (int s2 = 128; s2 > 0; s2 >>= 1) {
        if (tid < s2) red[tid] += red[tid + s2];
        __syncthreads();
    }
    float scale = rsqrtf(red[0] / (float)Dd + EPSf);
    float pl[Ee];
    #pragma unroll
    for (int e = 0; e < Ee; e++) pl[e] = 0.f;
    #pragma unroll
    for (int i = 0; i < 4; i++) {
        int d = tid + i * 256;
        float h = xv[i] * g[d] * scale;
        t2h[(size_t)row * Dd + d] = f2bf(h);
        const float4* rp = (const float4*)(rw + (size_t)d * Ee);
        float4 r0 = rp[0], r1 = rp[1];
        pl[0] += h * r0.x; pl[1] += h * r0.y; pl[2] += h * r0.z; pl[3] += h * r0.w;
        pl[4] += h * r1.x; pl[5] += h * r1.y; pl[6] += h * r1.z; pl[7] += h * r1.w;
    }
    #pragma unroll
    for (int off = 32; off > 0; off >>= 1) {
        #pragma unroll
        for (int e = 0; e < Ee; e++) pl[e] += __shfl_xor(pl[e], off);
    }
    int wv = tid >> 6;
    if ((tid & 63) == 0) {
        #pragma unroll
        for (int e = 0; e < Ee; e++) pw[wv][e] = pl[e];
    }
    __syncthreads();
    if (tid == 0) {
        float p[Ee];
        #pragma unroll
        for (int e = 0; e < Ee; e++) p[e] = pw[0][e] + pw[1][e] + pw[2][e] + pw[3][e];
        int i0 = 0;
        for (int e = 1; e < Ee; e++) if (p[e] > p[i0]) i0 = e;
        int i1 = (i0 == 0) ? 1 : 0;
        for (int e = 0; e < Ee; e++) if (e != i0 && p[e] > p[i1]) i1 = e;
        float e1 = expf(p[i1] - p[i0]);
        float w0 = 1.f / (1.f + e1), w1 = e1 / (1.f + e1);
        gate_w[2 * row] = w0;
        gate_w[2 * row + 1] = w1;
        int p0 = atomicAdd(&counts[i0], 1);
        list_tok[i0 * Tt + p0] = row;
        list_gid[i0 * Tt + p0] = 2 * row;
        int p1 = atomicAdd(&counts[i1], 1);
        list_tok[i1 * Tt + p1] = row;
        list_gid[i1 * Tt + p1] = 2 * row + 1;
    }
}

// ---------------------------------------------------------------------------
// Pipelined MFMA GEMM. Block tile = (32*BMW) x (32*BNW), waves 2x2 (each wave
// BMW x BNW grid of 16x16 MFMA tiles), BK=32, software-pipelined global->reg
// ->LDS staging. A = bf16 planes (hi/lo if SPLIT), b128 staged. B = f32 HBM,
// converted to bf16 hi(/lo) in staging epilogue; LDS [n][k] stride 40 with
// XOR chunk swizzle (conflict-lean, b128 fragment reads) — verified R4.
// SPLIT: 3-MFMA f32 fidelity (hi*hi + lo*hi + hi*lo). GLU: second B, silu
// epilogue. GATHER: rows via lists. EPI: 0 f32; 1 split bf16; 2 +resid f32;
// 3 GLU bf16; 4 atomic gate scatter. ZM: 0 none; 1 qkv-z; 2 moe-z.
template <int BMW, int BNW, int SPLIT, int GLU, int GATHER, int EPI, int ZM>
__global__ __launch_bounds__(256) void gemm_k(
    const u16* __restrict__ Ah, const u16* __restrict__ Al,
    const float* __restrict__ B1, const float* __restrict__ B3,
    const float* __restrict__ B2,
    int M, int N, int Kd, int lda, int ldb, int ldc, long bzs, long czs,
    const int* __restrict__ arow, const int* __restrict__ crow,
    const int* __restrict__ cntp, const float* __restrict__ gate_f,
    float* __restrict__ Cf, u16* __restrict__ Chi, u16* __restrict__ Clo,
    const float* __restrict__ residf, u16* __restrict__ Cbf) {
    constexpr int BM = 32 * BMW, BN = 32 * BNW;
    constexpr int AR = BMW / 2;            // A rows staged per thread
    constexpr int BI = BNW / 2;            // B k-row groups per thread
    constexpr int TPR = BN / 8;            // threads per B k-row
    constexpr int STEP = 256 / TPR;
    __shared__ __align__(16) u16 Ash[BM * 40];
    __shared__ __align__(16) u16 Asl[SPLIT ? BM * 40 : 8];
    __shared__ __align__(16) u16 Bsh[BN * 40];
    __shared__ __align__(16) u16 Bsx[(SPLIT || GLU) ? BN * 40 : 8];

    int tid = threadIdx.x;
    int row0 = blockIdx.y * BM, col0 = blockIdx.x * BN;
    int z = ZM ? blockIdx.z : 0;
    const float* Bp = B1;
    const float* B3p = B3;
    if (ZM == 1) Bp = (z == 0) ? B1 : ((z == 1) ? B3 : B2);
    if (ZM == 2) {
        Bp = B1 + (size_t)z * bzs;
        if (GLU) B3p = B3 + (size_t)z * bzs;
    }
    const int* arp = arow;
    const int* crp = crow;
    if (ZM == 2 && GATHER) { arp = arow + z * Tt; crp = crow + z * Tt; }
    int cnt = GATHER ? cntp[ZM == 2 ? z : 0] : M;
    if (row0 >= cnt) return;
    float* Cfp = (ZM == 1) ? (Cf + (size_t)z * czs) : Cf;

    int lane = tid & 63, wv = tid >> 6;
    int m = lane & 15, qq = lane >> 4;
    int wrow = wv >> 1, wcol = wv & 1;
    int rbase = wrow * BMW * 16, cbase = wcol * BNW * 16;

    f32x4 acc[BMW][BNW];
    f32x4 acc3[GLU ? BMW : 1][GLU ? BNW : 1];
    #pragma unroll
    for (int i = 0; i < BMW; i++)
        #pragma unroll
        for (int j = 0; j < BNW; j++) acc[i][j] = (f32x4){0.f, 0.f, 0.f, 0.f};
    if (GLU) {
        #pragma unroll
        for (int i = 0; i < BMW; i++)
            #pragma unroll
            for (int j = 0; j < BNW; j++) acc3[i][j] = (f32x4){0.f, 0.f, 0.f, 0.f};
    }

    // --- staging assignments ---
    int rak = (tid & 3) * 8;                 // A k-offset
    const u16* pA[AR]; const u16* pAl[AR]; int rloc[AR];
    #pragma unroll
    for (int i = 0; i < AR; i++) {
        rloc[i] = i * 64 + (tid >> 2);
        int ar = row0 + rloc[i];
        if (GATHER) ar = arp[min(ar, cnt - 1)];
        pA[i] = Ah + (size_t)ar * lda + rak;
        if (SPLIT) pAl[i] = Al + (size_t)ar * lda + rak;
    }
    int rbl[BI], ncb = (tid % TPR) * 8;
    #pragma unroll
    for (int i = 0; i < BI; i++) rbl[i] = i * STEP + tid / TPR;

    uint4 rAh[AR], rAl[SPLIT ? AR : 1];
    float4 rB[BI][2], rB3[GLU ? BI : 1][2];

    auto loadT = [&](int k0) {
        #pragma unroll
        for (int i = 0; i < AR; i++) {
            rAh[i] = *(const uint4*)(pA[i] + k0);
            if (SPLIT) rAl[i] = *(const uint4*)(pAl[i] + k0);
        }
        #pragma unroll
        for (int i = 0; i < BI; i++) {
            const float* pB = Bp + (size_t)(k0 + rbl[i]) * ldb + col0 + ncb;
            rB[i][0] = *(const float4*)pB;
            rB[i][1] = *(const float4*)(pB + 4);
            if (GLU) {
                const float* pB3 = B3p + (size_t)(k0 + rbl[i]) * ldb + col0 + ncb;
                rB3[i][0] = *(const float4*)pB3;
                rB3[i][1] = *(const float4*)(pB3 + 4);
            }
        }
    };
    auto storeT = [&]() {
        #pragma unroll
        for (int i = 0; i < AR; i++) {
            *(uint4*)(Ash + rloc[i] * 40 + rak) = rAh[i];
            if (SPLIT) *(uint4*)(Asl + rloc[i] * 40 + rak) = rAl[i];
        }
        #pragma unroll
        for (int i = 0; i < BI; i++) {
            int rb = rbl[i], cb = rb >> 3, rb7 = rb & 7;
            float bb[8];
            *(float4*)&bb[0] = rB[i][0]; *(float4*)&bb[4] = rB[i][1];
            #pragma unroll
            for (int j = 0; j < 8; j++) {
                int n = ncb + j;
                int koff = (((cb ^ ((n >> 3) & 3)) << 3) | rb7);
                u16 hi = f2bf(bb[j]);
                Bsh[n * 40 + koff] = hi;
                if (SPLIT) Bsx[n * 40 + koff] = f2bf(bb[j] - bf2f(hi));
            }
            if (GLU) {
                float cc[8];
                *(float4*)&cc[0] = rB3[i][0]; *(float4*)&cc[4] = rB3[i][1];
                #pragma unroll
                for (int j = 0; j < 8; j++) {
                    int n = ncb + j;
                    int koff = (((cb ^ ((n >> 3) & 3)) << 3) | rb7);
                    Bsx[n * 40 + koff] = f2bf(cc[j]);
                }
            }
        }
    };

    loadT(0);
    int nk = Kd / 32;
    for (int kc = 0; kc < nk; kc++) {
        storeT();
        __syncthreads();
        if (kc + 1 < nk) loadT((kc + 1) * 32);
        s16x8 afh[BMW], afl[SPLIT ? BMW : 1], bfh[BNW], bfx[(SPLIT || GLU) ? BNW : 1];
        #pragma unroll
        for (int mt = 0; mt < BMW; mt++) {
            int off = (rbase + mt * 16 + m) * 40 + qq * 8;
            afh[mt] = *(const s16x8*)(Ash + off);
            if (SPLIT) afl[mt] = *(const s16x8*)(Asl + off);
        }
        #pragma unroll
        for (int ct = 0; ct < BNW; ct++) {
            int n = cbase + ct * 16 + m;
            int off = n * 40 + (qq ^ ((n >> 3) & 3)) * 8;
            bfh[ct] = *(const s16x8*)(Bsh + off);
            if (SPLIT || GLU) bfx[ct] = *(const s16x8*)(Bsx + off);
        }
        #pragma unroll
        for (int mt = 0; mt < BMW; mt++) {
            #pragma unroll
            for (int ct = 0; ct < BNW; ct++) {
                acc[mt][ct] = __builtin_amdgcn_mfma_f32_16x16x32_bf16(afh[mt], bfh[ct], acc[mt][ct], 0, 0, 0);
                if (SPLIT) {
                    acc[mt][ct] = __builtin_amdgcn_mfma_f32_16x16x32_bf16(afl[mt], bfh[ct], acc[mt][ct], 0, 0, 0);
                    acc[mt][ct] = __builtin_amdgcn_mfma_f32_16x16x32_bf16(afh[mt], bfx[ct], acc[mt][ct], 0, 0, 0);
                }
                if (GLU)
                    acc3[mt][ct] = __builtin_amdgcn_mfma_f32_16x16x32_bf16(afh[mt], bfx[ct], acc3[mt][ct], 0, 0, 0);
            }
        }
        __syncthreads();
    }
    // epilogue — C/D layout: col = lane&15, row = (lane>>4)*4 + reg (m89/m91)
    #pragma unroll
    for (int mt = 0; mt < BMW; mt++) {
        #pragma unroll
        for (int ct = 0; ct < BNW; ct++) {
            #pragma unroll
            for (int rg = 0; rg < 4; rg++) {
                int gr = row0 + rbase + mt * 16 + qq * 4 + rg;
                int gc = col0 + cbase + ct * 16 + m;
                if (GATHER && gr >= cnt) continue;
                float v = acc[mt][ct][rg];
                if (EPI == 4) {
                    int gid = crp[gr];
                    atomicAdd(&Cfp[(size_t)(gid >> 1) * ldc + gc], gate_f[gid] * v);
                    continue;
                }
                size_t cix;
                if (GATHER) cix = (size_t)crp[gr] * ldc + gc;
                else cix = (size_t)gr * ldc + gc;
                if (EPI == 0) {
                    Cfp[cix] = v;
                } else if (EPI == 1) {
                    u16 hi = f2bf(v);
                    Chi[cix] = hi;
                    Clo[cix] = f2bf(v - bf2f(hi));
                } else if (EPI == 2) {
                    Cfp[cix] = v + residf[cix];
                } else if (EPI == 3) {
                    float sg = v / (1.f + expf(-v));
                    Cbf[cix] = f2bf(sg * acc3[mt][ct][rg]);
                }
            }
        }
    }
}

// ---------------------------------------------------------------------------
__global__ __launch_bounds__(256) void rope_k(float* __restrict__ q, float* __restrict__ k) {
    int t = blockIdx.x, tid = threadIdx.x;
    int h = tid >> 4, i = tid & 15;
    int pos = t & (Ss - 1);
    float inv = powf(THETAf, -((float)(2 * i)) / (float)HDd);
    float ang = (float)pos * inv;
    float c = cosf(ang), sn = sinf(ang);
    size_t base = (size_t)t * Ll + h * HDd + 2 * i;
    float q1 = q[base], q2 = q[base + 1];
    q[base] = q1 * c - q2 * sn;
    q[base + 1] = q1 * sn + q2 * c;
    float k1 = k[base], k2 = k[base + 1];
    k[base] = k1 * c - k2 * sn;
    k[base + 1] = k1 * sn + k2 * c;
}

// ---------------------------------------------------------------------------
// MFMA flash attention (verified R4). Block = 64-row Q-tile, split-bf16.
__global__ __launch_bounds__(256) void attn_k(const float* __restrict__ qf,
                                              const float* __restrict__ kf,
                                              const float* __restrict__ vf,
                                              u16* __restrict__ ohi, u16* __restrict__ olo) {
    const float SCALE = 0.1767766952966369f; // 1/sqrt(32)
    int qt = blockIdx.x;
    int bh = blockIdx.y;
    int h = bh & (Hh - 1), b = bh >> 4;
    int tid = threadIdx.x;
    int wv = tid >> 6, lane = tid & 63;
    int m = lane & 15, quad = lane >> 4;

    __shared__ __align__(16) u16 Ksh[64 * 40];
    __shared__ __align__(16) u16 Ksl[64 * 40];
    __shared__ __align__(16) u16 Vsh[32 * 72];
    __shared__ __align__(16) u16 Vsl[32 * 72];
    __shared__ __align__(16) u16 Ph[4][16 * 72];
    __shared__ __align__(16) u16 Pl[4][16 * 72];

    int qrow = qt * 64 + wv * 16 + m;
    const float* qp = qf + (size_t)(b * Ss + qrow) * Ll + h * HDd + quad * 8;
    float4 q0 = *(const float4*)qp;
    float4 q1 = *(const float4*)(qp + 4);
    float qvv[8] = {q0.x, q0.y, q0.z, q0.w, q1.x, q1.y, q1.z, q1.w};
    s16x8 qh, ql;
    #pragma unroll
    for (int j = 0; j < 8; j++) {
        u16 hi = f2bf(qvv[j]);
        qh[j] = (short)hi;
        ql[j] = (short)f2bf(qvv[j] - bf2f(hi));
    }

    float mrun[4], lrun[4];
    f32x4 o0 = (f32x4){0.f, 0.f, 0.f, 0.f};
    f32x4 o1 = (f32x4){0.f, 0.f, 0.f, 0.f};
    #pragma unroll
    for (int rg = 0; rg < 4; rg++) { mrun[rg] = -1e30f; lrun[rg] = 0.f; }

    int skey = tid >> 2, sd0 = (tid & 3) * 8;
    for (int kt = 0; kt <= qt; kt++) {
        int kbase = kt * 64;
        {
            const float* kp = kf + (size_t)(b * Ss + kbase + skey) * Ll + h * HDd + sd0;
            float4 a0 = *(const float4*)kp;
            float4 a1 = *(const float4*)(kp + 4);
            float kvv[8] = {a0.x, a0.y, a0.z, a0.w, a1.x, a1.y, a1.z, a1.w};
            s16x8 khv, klv;
            #pragma unroll
            for (int j = 0; j < 8; j++) {
                u16 hi = f2bf(kvv[j]);
                khv[j] = (short)hi;
                klv[j] = (short)f2bf(kvv[j] - bf2f(hi));
            }
            *(s16x8*)(Ksh + skey * 40 + sd0) = khv;
            *(s16x8*)(Ksl + skey * 40 + sd0) = klv;
            const float* vp = vf + (size_t)(b * Ss + kbase + skey) * Ll + h * HDd + sd0;
            float4 c0 = *(const float4*)vp;
            float4 c1 = *(const float4*)(vp + 4);
            float vvv[8] = {c0.x, c0.y, c0.z, c0.w, c1.x, c1.y, c1.z, c1.w};
            #pragma unroll
            for (int j = 0; j < 8; j++) {
                int d = sd0 + j;
                int c2 = (skey >> 3) ^ ((d >> 3) & 7);
                int koff = (c2 << 3) | (skey & 7);
                u16 hi = f2bf(vvv[j]);
                Vsh[d * 72 + koff] = hi;
                Vsl[d * 72 + koff] = f2bf(vvv[j] - bf2f(hi));
            }
        }
        __syncthreads();
        f32x4 sc[4];
        #pragma unroll
        for (int ct = 0; ct < 4; ct++) {
            int n = ct * 16 + m;
            s16x8 kh = *(const s16x8*)(Ksh + n * 40 + quad * 8);
            s16x8 kl = *(const s16x8*)(Ksl + n * 40 + quad * 8);
            f32x4 a = (f32x4){0.f, 0.f, 0.f, 0.f};
            a = __builtin_amdgcn_mfma_f32_16x16x32_bf16(qh, kh, a, 0, 0, 0);
            a = __builtin_amdgcn_mfma_f32_16x16x32_bf16(ql, kh, a, 0, 0, 0);
            a = __builtin_amdgcn_mfma_f32_16x16x32_bf16(qh, kl, a, 0, 0, 0);
            sc[ct] = a;
        }
        #pragma unroll
        for (int rg = 0; rg < 4; rg++) {
            int qr = qt * 64 + wv * 16 + quad * 4 + rg;
            float s4[4];
            #pragma unroll
            for (int ct = 0; ct < 4; ct++) {
                float sv = sc[ct][rg] * SCALE;
                if (kbase + ct * 16 + m > qr) sv = -1e30f;
                s4[ct] = sv;
            }
            float tm = fmaxf(fmaxf(s4[0], s4[1]), fmaxf(s4[2], s4[3]));
            #pragma unroll
            for (int off = 8; off > 0; off >>= 1) tm = fmaxf(tm, __shfl_xor(tm, off));
            float mnew = fmaxf(mrun[rg], tm);
            float psum = 0.f;
            float p4[4];
            #pragma unroll
            for (int ct = 0; ct < 4; ct++) {
                p4[ct] = expf(s4[ct] - mnew);
                psum += p4[ct];
            }
            #pragma unroll
            for (int off = 8; off > 0; off >>= 1) psum += __shfl_xor(psum, off);
            float alpha = expf(mrun[rg] - mnew);
            mrun[rg] = mnew;
            lrun[rg] = lrun[rg] * alpha + psum;
            o0[rg] *= alpha;
            o1[rg] *= alpha;
            int prow = quad * 4 + rg;
            #pragma unroll
            for (int ct = 0; ct < 4; ct++) {
                u16 hi = f2bf(p4[ct]);
                Ph[wv][prow * 72 + ct * 16 + m] = hi;
                Pl[wv][prow * 72 + ct * 16 + m] = f2bf(p4[ct] - bf2f(hi));
            }
        }
        #pragma unroll
        for (int kc = 0; kc < 2; kc++) {
            s16x8 pah = *(const s16x8*)(Ph[wv] + m * 72 + kc * 32 + quad * 8);
            s16x8 pal = *(const s16x8*)(Pl[wv] + m * 72 + kc * 32 + quad * 8);
            #pragma unroll
            for (int ct = 0; ct < 2; ct++) {
                int d = ct * 16 + m;
                int c2 = (kc * 4 + quad) ^ ((d >> 3) & 7);
                s16x8 vh = *(const s16x8*)(Vsh + d * 72 + c2 * 8);
                s16x8 vl2 = *(const s16x8*)(Vsl + d * 72 + c2 * 8);
                if (ct == 0) {
                    o0 = __builtin_amdgcn_mfma_f32_16x16x32_bf16(pah, vh, o0, 0, 0, 0);
                    o0 = __builtin_amdgcn_mfma_f32_16x16x32_bf16(pal, vh, o0, 0, 0, 0);
                    o0 = __builtin_amdgcn_mfma_f32_16x16x32_bf16(pah, vl2, o0, 0, 0, 0);
                } else {
                    o1 = __builtin_amdgcn_mfma_f32_16x16x32_bf16(pah, vh, o1, 0, 0, 0);
                    o1 = __builtin_amdgcn_mfma_f32_16x16x32_bf16(pal, vh, o1, 0, 0, 0);
                    o1 = __builtin_amdgcn_mfma_f32_16x16x32_bf16(pah, vl2, o1, 0, 0, 0);
                }
            }
        }
        __syncthreads();
    }
    #pragma unroll
    for (int rg = 0; rg < 4; rg++) {
        float inv = 1.f / lrun[rg];
        int tok = b * Ss + qt * 64 + wv * 16 + quad * 4 + rg;
        #pragma unroll
        for (int ct = 0; ct < 2; ct++) {
            float ov = (ct ? o1[rg] : o0[rg]) * inv;
            int d = ct * 16 + m;
            u16 hi = f2bf(ov);
            ohi[(size_t)tok * Ll + h * HDd + d] = hi;
            olo[(size_t)tok * Ll + h * HDd + d] = f2bf(ov - bf2f(hi));
        }
    }
}

// ---------------------------------------------------------------------------
__global__ __launch_bounds__(256) void final_k(const float* __restrict__ x2,
                                               float* __restrict__ out) {
    int t = blockIdx.x, tid = threadIdx.x;
    #pragma unroll
    for (int i = 0; i < 4; i++) {
        int d = tid + i * 256;
        size_t ix = (size_t)t * Dd + d;
        out[ix] = out[ix] + x2[ix];
    }
}

// ---------------------------------------------------------------------------
extern "C" void kernel_launch(void* const* d_in, const int* in_sizes, int n_in,
                              void* d_out, int out_size, void* d_ws, size_t ws_size,
                              hipStream_t stream) {
    const float* x       = (const float*)d_in[0];
    const float* g1      = (const float*)d_in[1];
    const float* g2      = (const float*)d_in[2];
    const float* w_down  = (const float*)d_in[3];
    const float* wq      = (const float*)d_in[4];
    const float* wk      = (const float*)d_in[5];
    const float* wv      = (const float*)d_in[6];
    const float* w_up    = (const float*)d_in[7];
    const float* rw      = (const float*)d_in[8];
    const float* w1      = (const float*)d_in[9];
    const float* w3      = (const float*)d_in[10];
    const float* w2      = (const float*)d_in[11];
    float* out = (float*)d_out;

    // --- workspace overlay (~32.2 MB) ---
    char* S = (char*)d_ws;                          // 16 MB time-shared
    u16*   h_hi = (u16*)(S + (size_t)0);            // phase 1
    u16*   h_lo = (u16*)(S + ((size_t)4 << 20));
    float* qf   = (float*)(S + (size_t)0);          // phase 2 (h dead)
    float* kf   = (float*)(S + ((size_t)4 << 20));
    float* vf   = (float*)(S + ((size_t)8 << 20));
    u16*   o_hi = (u16*)(S + ((size_t)12 << 20));
    u16*   o_lo = (u16*)(S + ((size_t)14 << 20));
    u16*   hid  = (u16*)(S + (size_t)0);            // phase 4
    char* p = (char*)d_ws + ((size_t)16 << 20);
    u16*   c_hi   = (u16*)p;   p += (size_t)Tt * Ll * 2;
    u16*   c_lo   = (u16*)p;   p += (size_t)Tt * Ll * 2;
    u16*   t2h    = (u16*)p;   p += (size_t)Tt * Dd * 2;
    float* x2f    = (float*)p; p += (size_t)Tt * Dd * 4;
    float* gate_w = (float*)p; p += (size_t)Tt * 2 * 4;
    int*   counts = (int*)p;   p += 256;
    int*   l_tok  = (int*)p;   p += (size_t)Ee * Tt * 4;
    int*   l_gid  = (int*)p;   p += (size_t)Ee * Tt * 4;

    hipMemsetAsync(counts, 0, 256, stream);
    hipMemsetAsync(out, 0, (size_t)Tt * Dd * 4, stream);  // MoE accumulator

    rmsnorm1_k<<<Tt, 256, 0, stream>>>(x, g1, h_hi, h_lo);

    // c = h @ w_down  (64x64 split, split-out)
    gemm_k<2, 2, 1, 0, 0, 1, 0><<<dim3(Ll / 64, Tt / 64), 256, 0, stream>>>(
        h_hi, h_lo, w_down, nullptr, nullptr, Tt, Ll, Dd, Dd, Ll, Ll, 0, 0,
        nullptr, nullptr, nullptr, nullptr, nullptr, c_hi, c_lo, nullptr, nullptr);

    // q,k,v = c @ {wq,wk,wv}  (64x64 split, z=3)
    gemm_k<2, 2, 1, 0, 0, 0, 1><<<dim3(Ll / 64, Tt / 64, 3), 256, 0, stream>>>(
        c_hi, c_lo, wq, wk, wv, Tt, Ll, Ll, Ll, Ll, Ll, 0, (long)Tt * Ll,
        nullptr, nullptr, nullptr, nullptr, qf, nullptr, nullptr, nullptr, nullptr);

    rope_k<<<Tt, 256, 0, stream>>>(qf, kf);

    attn_k<<<dim3(Ss / 64, Bb * Hh), 256, 0, stream>>>(qf, kf, vf, o_hi, o_lo);

    // x2 = x + o @ w_up  (64x64 split, residual)
    gemm_k<2, 2, 1, 0, 0, 2, 0><<<dim3(Dd / 64, Tt / 64), 256, 0, stream>>>(
        o_hi, o_lo, w_up, nullptr, nullptr, Tt, Dd, Ll, Ll, Dd, Dd, 0, 0,
        nullptr, nullptr, nullptr, nullptr, x2f, nullptr, nullptr, x, nullptr);

    rmsnorm2_router_k<<<Tt, 256, 0, stream>>>(x2f, g2, rw, t2h, gate_w,
                                              counts, l_tok, l_gid);

    // MoE GLU (128x64, z=8)
    gemm_k<4, 2, 0, 1, 1, 3, 2><<<dim3(Ff / 64, Tt / 128, Ee), 256, 0, stream>>>(
        t2h, nullptr, w1, w3, nullptr, Tt, Ff, Dd, Dd, Ff, Ff,
        (long)Dd * Ff, 0, l_tok, l_gid, counts, nullptr,
        nullptr, nullptr, nullptr, nullptr, hid);

    // MoE down (128x128, z=8), atomic gated combine into out
    gemm_k<4, 4, 0, 0, 1, 4, 2><<<dim3(Dd / 128, Tt / 128, Ee), 256, 0, stream>>>(
        hid, nullptr, w2, nullptr, nullptr, Tt, Dd, Ff, Ff, Dd, Dd,
        (long)Ff * Dd, 0, l_gid, l_gid, counts, gate_w,
        out, nullptr, nullptr, nullptr, nullptr);

    final_k<<<Tt, 256, 0, stream>>>(x2f, out);
}